// Round 11
// baseline (178.647 us; speedup 1.0000x reference)
//
#include <hip/hip_runtime.h>
#include <hip/hip_bf16.h>

// LSTM cell, B=8192, IN=H=1024.
// R11: 2 blocks/CU for inter-block MFMA/LDS overlap — tile 256x128, 4 waves
// (128x64 each), BK=32 dbuf, 48 KiB LDS, ~200 regs, launch_bounds(256,2).
// No manual lgkm drains (compiler counted waits); 2 barriers + vmcnt(6)/K-tile.

#define B_DIM 8192
#define H_DIM 1024
#define BH (8192 * 1024)
#define K2 2048

typedef __attribute__((ext_vector_type(4))) float f32x4;
typedef __attribute__((ext_vector_type(8))) __bf16 bf16x8;
typedef __attribute__((ext_vector_type(8))) unsigned short ushort8;

static __device__ __forceinline__ unsigned short f2bf(float f) {
    return __builtin_bit_cast(unsigned short, (__bf16)f);
}
static __device__ __forceinline__ float sigf(float x) {
    return 1.0f / (1.0f + __expf(-x));
}
static __device__ __forceinline__ float tanhft(float x) {
    float e = __expf(2.0f * x);
    return (e - 1.0f) / (e + 1.0f);
}
static __device__ __forceinline__ void gload16(const void* g, void* l) {
    __builtin_amdgcn_global_load_lds(
        (const __attribute__((address_space(1))) unsigned int*)g,
        (__attribute__((address_space(3))) unsigned int*)l, 16, 0, 0);
}
static __device__ __forceinline__ ushort8 cvt8(const float* src) {
    const float4 u = ((const float4*)src)[0];
    const float4 v = ((const float4*)src)[1];
    ushort8 o;
    o[0] = f2bf(u.x); o[1] = f2bf(u.y); o[2] = f2bf(u.z); o[3] = f2bf(u.w);
    o[4] = f2bf(v.x); o[5] = f2bf(v.y); o[6] = f2bf(v.z); o[7] = f2bf(v.w);
    return o;
}

// ---- merged conversion kernel ----
// blocks [0,8192):    A_bf[b][k] = k<1024 ? x[b][k] : h[b][k-1024]
// blocks [8192,12288): W'[n][k]: n = jb*128 + g*32 + wn*16 + jj (jb:32,g:4,wn:2,jj:16)
//                      source row = g*1024 + jb*32 + wn*16 + jj
__global__ __launch_bounds__(256) void conv_kernel(
    const float* __restrict__ x, const float* __restrict__ h,
    const float* __restrict__ Wx, const float* __restrict__ Wh,
    unsigned short* __restrict__ A, unsigned short* __restrict__ W)
{
    const int bidx = blockIdx.x;
    if (bidx < 8192) {
        const int id = bidx * 256 + threadIdx.x;
        const int base = id * 8;
        const int b = base >> 11;
        const int k = base & 2047;
        const float* src = (k < 1024) ? (x + (size_t)b * 1024 + k)
                                      : (h + (size_t)b * 1024 + (k - 1024));
        *(ushort8*)(A + base) = cvt8(src);
    } else {
        const int id = (bidx - 8192) * 256 + threadIdx.x;
        const int base = id * 8;
        const int n = base >> 11;
        const int k = base & 2047;
        const int jb = n >> 7, loc = n & 127;
        const int g = loc >> 5, wn = (loc >> 4) & 1, jj = loc & 15;
        const int srow = (g << 10) + (jb << 5) + (wn << 4) + jj;
        const float* src = (k < 1024) ? (Wx + (size_t)srow * 1024 + k)
                                      : (Wh + (size_t)srow * 1024 + (k - 1024));
        *(ushort8*)(W + base) = cvt8(src);
    }
}

// ==================== 256x128 GEMM, BK=32, 4 waves, 2 blocks/CU ====================
// LDS 48 KiB (u16 units): buf*12288 | A rows[256]x32 (8192 u16) | B at +8192 rows[128]x32.
// Element (row r, k): r*32 + ((k8 ^ ((r>>1)&3))<<3) + (k&7).  Stage: chunk ci
// (row=ci>>2, pre-swz k8=(ci&3)^((ci>>3)&3)) -> linear dest ci*16B.
__global__ __launch_bounds__(256, 2) void lstm_gemm(
    const unsigned short* __restrict__ Abf, const unsigned short* __restrict__ Wbf,
    const float* __restrict__ bx, const float* __restrict__ bh,
    const float* __restrict__ cprev, float* __restrict__ out)
{
    extern __shared__ unsigned short lds[];

    const int tid = threadIdx.x;
    const int lane = tid & 63;
    const int wv = tid >> 6;         // 0..3
    const int wm = wv >> 1;          // 0..1
    const int wn = wv & 1;           // 0..1
    const int q = lane >> 4, c = lane & 15;

    // XCD-chunked: xcd owns jb quad (W slice 2 MiB, L2-resident); 1024 blocks
    const int bid = blockIdx.x;
    const int xcd = bid & 7;
    const int idx = bid >> 3;              // 0..127
    const int jb  = xcd * 4 + (idx & 3);   // 0..31
    const int bb  = idx >> 2;              // 0..31
    const int b0 = bb * 256;

    const unsigned short* Ab = Abf + (size_t)b0 * K2;
    const unsigned short* Wb = Wbf + (size_t)(jb * 128) * K2;

    // staging: per-gload thread covers chunk tid + 256*k4
    const size_t ssg = (size_t)(tid >> 2) * K2
                     + (size_t)(((tid & 3) ^ ((tid >> 3) & 3)) * 8);
    const unsigned sdA = (unsigned)(tid & 192) * 8;  // wave-uniform base

    // fragment reads: phys chunk = q ^ ((row>>1)&3); (row>>1)&3 == (c>>1)&3
    const unsigned cqa = (unsigned)((q ^ ((c >> 1) & 3)) << 3);
    const unsigned aBase = (unsigned)(wm * 128 + c) * 32 + cqa;           // + mt*512
    const unsigned bBase = 8192u + (unsigned)(wn * 16 + c) * 32 + cqa;    // + g*1024

    f32x4 acc[8][4];
#pragma unroll
    for (int m = 0; m < 8; ++m)
#pragma unroll
        for (int g = 0; g < 4; ++g) acc[m][g] = f32x4{0.f, 0.f, 0.f, 0.f};

    bf16x8 av[8], bv[4];

#define STG(BUF, T) do {                                                       \
    const size_t _t = (size_t)((T) & 63) * 32;                                 \
    gload16(Ab + ssg + _t,                &lds[(BUF) * 12288 + sdA]);          \
    gload16(Ab + ssg + (size_t)64 * K2 + _t,  &lds[(BUF) * 12288 + 2048 + sdA]);\
    gload16(Ab + ssg + (size_t)128 * K2 + _t, &lds[(BUF) * 12288 + 4096 + sdA]);\
    gload16(Ab + ssg + (size_t)192 * K2 + _t, &lds[(BUF) * 12288 + 6144 + sdA]);\
    gload16(Wb + ssg + _t,                &lds[(BUF) * 12288 + 8192 + sdA]);   \
    gload16(Wb + ssg + (size_t)64 * K2 + _t, &lds[(BUF) * 12288 + 10240 + sdA]);\
} while (0)

#define RD(BUF) do {                                                           \
    const unsigned short* _pa = lds + (BUF) * 12288 + aBase;                   \
    const unsigned short* _pb = lds + (BUF) * 12288 + bBase;                   \
    bv[0] = *(const bf16x8*)(_pb);                                             \
    bv[1] = *(const bf16x8*)(_pb + 1024);                                      \
    bv[2] = *(const bf16x8*)(_pb + 2048);                                      \
    bv[3] = *(const bf16x8*)(_pb + 3072);                                      \
    av[0] = *(const bf16x8*)(_pa);                                             \
    av[1] = *(const bf16x8*)(_pa + 512);                                       \
    av[2] = *(const bf16x8*)(_pa + 1024);                                      \
    av[3] = *(const bf16x8*)(_pa + 1536);                                      \
    av[4] = *(const bf16x8*)(_pa + 2048);                                      \
    av[5] = *(const bf16x8*)(_pa + 2560);                                      \
    av[6] = *(const bf16x8*)(_pa + 3072);                                      \
    av[7] = *(const bf16x8*)(_pa + 3584);                                      \
} while (0)

#define MFMA32() do {                                                          \
    __builtin_amdgcn_s_setprio(1);                                             \
    _Pragma("unroll")                                                          \
    for (int _i = 0; _i < 8; ++_i)                                             \
        _Pragma("unroll")                                                      \
        for (int _g = 0; _g < 4; ++_g)                                         \
            acc[_i][_g] = __builtin_amdgcn_mfma_f32_16x16x32_bf16(             \
                av[_i], bv[_g], acc[_i][_g], 0, 0, 0);                         \
    __builtin_amdgcn_s_setprio(0);                                             \
} while (0)

#define BAR()  __builtin_amdgcn_s_barrier()
#define WVM6() asm volatile("s_waitcnt vmcnt(6)" ::: "memory")

// per K-tile: read 12 + 32 MFMAs (compiler-counted lgkm), barrier,
// stage t+2 over the just-consumed buffer, vmcnt(6) (retire t+1), barrier.
#define KTILE(BUF, T2) do {                                                    \
    RD(BUF);                                                                   \
    MFMA32();                                                                  \
    BAR();                                                                     \
    STG(BUF, T2);                                                              \
    WVM6();                                                                    \
    BAR();                                                                     \
} while (0)

    // prologue: tile0 -> buf0, tile1 -> buf1 (12 gloads); retire tile0's 6
    STG(0, 0); STG(1, 1);
    WVM6();
    BAR();

    for (int t = 0; t < 64; t += 2) {
        KTILE(0, t + 2);   // tile t   (buf0), stage t+2 -> buf0
        KTILE(1, t + 3);   // tile t+1 (buf1), stage t+3 -> buf1 (tail wraps, benign)
    }

#undef KTILE
#undef STG
#undef RD
#undef MFMA32

    // ---- fused LSTM epilogue (C/D: col=lane&15, row=(lane>>4)*4+rr) ----
    const int j = jb * 32 + wn * 16 + c;
    const float bI = bx[j] + bh[j];
    const float bF = bx[1024 + j] + bh[1024 + j];
    const float bG = bx[2048 + j] + bh[2048 + j];
    const float bO = bx[3072 + j] + bh[3072 + j];
#pragma unroll
    for (int mt = 0; mt < 8; ++mt) {
#pragma unroll
        for (int rr = 0; rr < 4; ++rr) {
            const int row = b0 + wm * 128 + mt * 16 + q * 4 + rr;
            const size_t off = (size_t)row * 1024 + j;
            const float iv = sigf(acc[mt][0][rr] + bI);
            const float fv = sigf(acc[mt][1][rr] + bF);
            const float gv = tanhft(acc[mt][2][rr] + bG);
            const float ov = sigf(acc[mt][3][rr] + bO);
            const float cp = cprev[off];
            const float nc = fv * cp + iv * gv;
            out[off] = ov * tanhft(nc);   // new_h
            out[BH + off] = nc;           // new_c
        }
    }
}

// ================== fallback (R2 128^2 kernel) if ws too small ==================
__global__ __launch_bounds__(256) void lstm_fallback(
    const float* __restrict__ incoming, const float* __restrict__ state,
    const float* __restrict__ Wx, const float* __restrict__ bx,
    const float* __restrict__ Wh, const float* __restrict__ bh,
    float* __restrict__ out)
{
    __shared__ unsigned short lA[128 * 64];
    __shared__ unsigned short lW[128 * 64];
    const int t = threadIdx.x;
    const int lane = t & 63;
    const int wv = t >> 6;
    const int q = lane >> 4;
    const int c = lane & 15;
    const int j0 = blockIdx.x * 32;
    const int b0 = blockIdx.y * 128;
    const float* hprev = state;
    const float* cprev = state + (size_t)BH;

    f32x4 acc[2][8];
#pragma unroll
    for (int mt = 0; mt < 2; ++mt)
#pragma unroll
        for (int nt = 0; nt < 8; ++nt)
            acc[mt][nt] = f32x4{0.f, 0.f, 0.f, 0.f};

    const int sr = t >> 3;
    const int sk8 = t & 7;

    for (int it = 0; it < 32; ++it) {
        const bool first = (it < 16);
        const float* As = first ? incoming : hprev;
        const float* Ws = first ? Wx : Wh;
        const int kk = first ? it * 64 : it * 64 - 1024;
#pragma unroll
        for (int i = 0; i < 4; ++i) {
            const int r = i * 32 + sr;
            *(ushort8*)&lA[r * 64 + ((sk8 ^ (r & 7)) * 8)] =
                cvt8(As + (size_t)(b0 + r) * 1024 + kk + sk8 * 8);
        }
#pragma unroll
        for (int i = 0; i < 4; ++i) {
            const int n = i * 32 + sr;
            const int grow = ((n >> 5) << 10) + j0 + (n & 31);
            *(ushort8*)&lW[n * 64 + ((sk8 ^ (n & 7)) * 8)] =
                cvt8(Ws + (size_t)grow * 1024 + kk + sk8 * 8);
        }
        __syncthreads();
#pragma unroll
        for (int ks = 0; ks < 2; ++ks) {
            const int k8a = ks * 4 + q;
            bf16x8 av[2], bv[8];
#pragma unroll
            for (int mt = 0; mt < 2; ++mt) {
                const int r = wv * 32 + mt * 16 + c;
                av[mt] = *(const bf16x8*)&lA[r * 64 + ((k8a ^ (r & 7)) * 8)];
            }
#pragma unroll
            for (int nt = 0; nt < 8; ++nt) {
                const int n = nt * 16 + c;
                bv[nt] = *(const bf16x8*)&lW[n * 64 + ((k8a ^ (n & 7)) * 8)];
            }
#pragma unroll
            for (int mt = 0; mt < 2; ++mt)
#pragma unroll
                for (int nt = 0; nt < 8; ++nt)
                    acc[mt][nt] = __builtin_amdgcn_mfma_f32_16x16x32_bf16(
                        av[mt], bv[nt], acc[mt][nt], 0, 0, 0);
        }
        __syncthreads();
    }

    const int b0r = b0 + wv * 32;
#pragma unroll
    for (int jt = 0; jt < 2; ++jt) {
        const int j = j0 + jt * 16 + c;
        const float bI = bx[j] + bh[j];
        const float bF = bx[1024 + j] + bh[1024 + j];
        const float bG = bx[2048 + j] + bh[2048 + j];
        const float bO = bx[3072 + j] + bh[3072 + j];
#pragma unroll
        for (int mt = 0; mt < 2; ++mt) {
#pragma unroll
            for (int rr = 0; rr < 4; ++rr) {
                const int row = b0r + mt * 16 + q * 4 + rr;
                const size_t off = (size_t)row * 1024 + j;
                const float iv = sigf(acc[mt][0 + jt][rr] + bI);
                const float fv = sigf(acc[mt][2 + jt][rr] + bF);
                const float gv = tanhft(acc[mt][4 + jt][rr] + bG);
                const float ov = sigf(acc[mt][6 + jt][rr] + bO);
                const float cp = cprev[off];
                const float nc = fv * cp + iv * gv;
                out[off] = ov * tanhft(nc);
                out[BH + off] = nc;
            }
        }
    }
}

extern "C" void kernel_launch(void* const* d_in, const int* in_sizes, int n_in,
                              void* d_out, int out_size, void* d_ws, size_t ws_size,
                              hipStream_t stream) {
    const float* incoming = (const float*)d_in[0];
    const float* state    = (const float*)d_in[1];
    const float* Wx       = (const float*)d_in[2];
    const float* bx       = (const float*)d_in[3];
    const float* Wh       = (const float*)d_in[4];
    const float* bh       = (const float*)d_in[5];
    float* out = (float*)d_out;

    const float* hprev = state;
    const float* cprev = state + (size_t)BH;

    const size_t A_bytes = (size_t)B_DIM * K2 * 2;       // 32 MiB
    const size_t W_bytes = (size_t)4 * H_DIM * K2 * 2;   // 16 MiB

    if (ws_size >= A_bytes + W_bytes) {
        unsigned short* Abf = (unsigned short*)d_ws;
        unsigned short* Wbf = (unsigned short*)((char*)d_ws + A_bytes);
        conv_kernel<<<dim3(12288), dim3(256), 0, stream>>>(
            incoming, hprev, Wx, Wh, Abf, Wbf);
        (void)hipFuncSetAttribute((const void*)lstm_gemm,
                                  hipFuncAttributeMaxDynamicSharedMemorySize, 49152);
        lstm_gemm<<<dim3(1024), dim3(256), 49152, stream>>>(
            Abf, Wbf, bx, bh, cprev, out);
    } else {
        dim3 grid(H_DIM / 32, B_DIM / 128);
        lstm_fallback<<<grid, dim3(256), 0, stream>>>(
            incoming, state, Wx, bx, Wh, bh, out);
    }
}